// Round 14
// baseline (404.407 us; speedup 1.0000x reference)
//
#include <hip/hip_runtime.h>
#include <hip/hip_fp16.h>

#define NN 8192
#define DDIM 128
#define DELTA 0.010f    // >= 2*delta_wc; delta_wc <= 2^-8 (bf16 MFMA) + f16 round
#define RPB 32          // rows per block (= MFMA M)
#define CAP 256         // window-candidate cap per row (expected <=60 worst-case bins)

typedef short short8 __attribute__((ext_vector_type(8)));
typedef float f32x16 __attribute__((ext_vector_type(16)));

__device__ __forceinline__ ushort bf16_rne(float v) {
    const unsigned x = __float_as_uint(v);
    return (ushort)((x + 0x7FFFu + ((x >> 16) & 1u)) >> 16);
}

// ---------------- Kernel 1: MLP (Linear->ReLU->Linear) + L2 normalize + bf16 copy ----
// f32 emb path FROZEN (bit-exact vs round-3/5 passing version); RNE bf16 mirror.
__global__ __launch_bounds__(128, 1)
void mlp_norm_kernel(const float* __restrict__ X, const float* __restrict__ W1,
                     const float* __restrict__ b1, const float* __restrict__ W2,
                     const float* __restrict__ b2, float* __restrict__ emb,
                     ushort* __restrict__ ebh, int rowsPerBlock)
{
    const int t = threadIdx.x;
    float4 w1r[32], w2r[32];
#pragma unroll
    for (int i = 0; i < 32; ++i) w1r[i] = *(const float4*)&W1[t * DDIM + i * 4];
#pragma unroll
    for (int i = 0; i < 32; ++i) w2r[i] = *(const float4*)&W2[t * DDIM + i * 4];
    const float bb1 = b1[t], bb2 = b2[t];

    __shared__ float sx[DDIM];
    __shared__ float sh[DDIM];
    __shared__ float wred[2];

    const int row0 = blockIdx.x * rowsPerBlock;
    for (int r = 0; r < rowsPerBlock; ++r) {
        const int row = row0 + r;
        sx[t] = X[(size_t)row * DDIM + t];
        __syncthreads();
        float acc = bb1;
#pragma unroll
        for (int i = 0; i < 32; ++i) {
            const float4 xv = *(const float4*)&sx[i * 4];
            acc = fmaf(xv.x, w1r[i].x, acc);
            acc = fmaf(xv.y, w1r[i].y, acc);
            acc = fmaf(xv.z, w1r[i].z, acc);
            acc = fmaf(xv.w, w1r[i].w, acc);
        }
        sh[t] = fmaxf(acc, 0.f);
        __syncthreads();
        float acc2 = bb2;
#pragma unroll
        for (int i = 0; i < 32; ++i) {
            const float4 hv = *(const float4*)&sh[i * 4];
            acc2 = fmaf(hv.x, w2r[i].x, acc2);
            acc2 = fmaf(hv.y, w2r[i].y, acc2);
            acc2 = fmaf(hv.z, w2r[i].z, acc2);
            acc2 = fmaf(hv.w, w2r[i].w, acc2);
        }
        float sq = acc2 * acc2;
#pragma unroll
        for (int off = 1; off < 64; off <<= 1) sq += __shfl_xor(sq, off);
        if ((t & 63) == 0) wred[t >> 6] = sq;
        __syncthreads();
        const float ss = wred[0] + wred[1];
        const float inv = 1.0f / fmaxf(sqrtf(ss), 1e-12f);
        const float v = acc2 * inv;
        emb[(size_t)row * DDIM + t] = v;
        ebh[(size_t)row * DDIM + t] = bf16_rne(v);
        __syncthreads();   // protect sx/sh/wred for next iteration
    }
}

// ---------------- Kernel 2: FUSED sim-GEMM + top-kp1 + exact fixup + ReLU write ------
// One block = 32 output rows. SINGLE-WRITER DISCIPLINE: every out[] address is written
// by exactly one store (pass 2: A-set values / zeros / overflow-zeros; rank phase:
// gathered window candidates, value-or-zero). No double-writes -> no cross-thread
// store-ordering assumptions. Select = bracket boundary-bin (t-hat in [L,H]); window
// [L-DELTA, H+DELTA]; window candidates recomputed EXACTLY (frozen fmaf chain,
// round-3-proven ordering) and ranked with lax.top_k tie-breaking.
__global__ __launch_bounds__(512, 1)
void fused_sim_topk(const ushort* __restrict__ ebh, const float* __restrict__ emb,
                    float* __restrict__ out, const int* __restrict__ kp1p)
{
    const int m0 = blockIdx.x * RPB;
    const int tid = threadIdx.x;
    const int lane = tid & 63, wid = tid >> 6;
    const int frow = lane & 31, fsel = lane >> 5;
    const unsigned kp1 = (unsigned)kp1p[0];

    __shared__ unsigned hist[RPB][256];     // 32 KB
    __shared__ float semb[RPB][129];        // 16.1 KB
    __shared__ unsigned rowLo[RPB], rowHi[RPB];
    __shared__ unsigned Acnt[RPB], cnum[RPB];
    __shared__ unsigned cand[RPB][CAP];     // 32 KB  (f16bits<<13 | col)
    __shared__ float cval[RPB][CAP];        // 32 KB

    for (int i = tid; i < RPB * 256; i += 512) ((unsigned*)hist)[i] = 0u;
    if (tid < RPB) { Acnt[tid] = 0u; cnum[tid] = 0u; }
    for (int i = tid; i < RPB * DDIM; i += 512)
        semb[i >> 7][i & 127] = emb[(size_t)(m0 + (i >> 7)) * DDIM + (i & 127)];

    // A fragments (this block's 32 rows) -> 32 VGPRs, loaded once
    short8 av[8];
    const ushort* pa = ebh + (size_t)(m0 + frow) * DDIM + fsel * 8;
#pragma unroll
    for (int ks = 0; ks < 8; ++ks) av[ks] = *(const short8*)&pa[ks * 16];
    __syncthreads();

    // ---- pass 1: histogram of f16(sim) bits (bins = f16 bits [13:6]) ----
    for (int s = 0; s < 32; ++s) {
        const int c0 = ((s << 3) + wid) << 5;            // waves interleaved on cols
        const ushort* pb = ebh + (size_t)(c0 + frow) * DDIM + fsel * 8;
        f32x16 acc;
#pragma unroll
        for (int q = 0; q < 16; ++q) acc[q] = 0.f;
#pragma unroll
        for (int ks = 0; ks < 8; ++ks) {
            const short8 bv = *(const short8*)&pb[ks * 16];
            acc = __builtin_amdgcn_mfma_f32_32x32x16_bf16(av[ks], bv, acc, 0, 0, 0);
        }
#pragma unroll
        for (int q = 0; q < 16; ++q) {
            const ushort hb = __half_as_ushort(__float2half_rn(acc[q]));
            if (hb != 0 && hb < 0x8000u) {
                const int rl = (q & 3) + 8 * (q >> 2) + 4 * fsel;
                atomicAdd(&hist[rl][hb >> 6], 1u);
            }
        }
    }
    __syncthreads();

    // ---- select: wave wid handles rows wid*4 .. wid*4+3 ----
    for (int rr = 0; rr < 4; ++rr) {
        const int r = wid * 4 + rr;
        const unsigned v = hist[r][lane * 4 + 0] + hist[r][lane * 4 + 1]
                         + hist[r][lane * 4 + 2] + hist[r][lane * 4 + 3];
        unsigned S = v;
#pragma unroll
        for (int off = 1; off < 64; off <<= 1) {
            const unsigned o = __shfl_down(S, off);
            if (lane + off < 64) S += o;
        }
        if (lane == 0 && S < kp1) { rowHi[r] = 0u; rowLo[r] = 0xFFFFFFFFu; } // keepall
        if (S >= kp1 && S - v < kp1) {           // unique boundary lane
            unsigned above = S - v;
            int j = 3;
            for (;;) {
                const unsigned hj = hist[r][lane * 4 + j];
                if (above + hj >= kp1 || j == 0) break;
                above += hj;
                --j;
            }
            const unsigned B = (unsigned)(lane * 4 + j);
            const float L = __half2float(__ushort_as_half((ushort)(B << 6)));
            const float H = __half2float(__ushort_as_half((ushort)((B << 6) | 63u)));
            const unsigned hi =
                (unsigned)__half_as_ushort(__float2half_rn(H + DELTA)) + 1u;
            const float lof = L - DELTA;
            unsigned lo;
            if (lof <= 0.f) lo = 1u;
            else { const unsigned l2 = __half_as_ushort(__float2half_rn(lof));
                   lo = (l2 > 1u) ? l2 - 1u : 1u; }
            rowHi[r] = hi; rowLo[r] = lo;
        }
    }
    __syncthreads();

    // ---- pass 2: recompute (bit-identical), single-writer stores, gather window ----
    for (int s = 0; s < 32; ++s) {
        const int c0 = ((s << 3) + wid) << 5;
        const ushort* pb = ebh + (size_t)(c0 + frow) * DDIM + fsel * 8;
        f32x16 acc;
#pragma unroll
        for (int q = 0; q < 16; ++q) acc[q] = 0.f;
#pragma unroll
        for (int ks = 0; ks < 8; ++ks) {
            const short8 bv = *(const short8*)&pb[ks * 16];
            acc = __builtin_amdgcn_mfma_f32_32x32x16_bf16(av[ks], bv, acc, 0, 0, 0);
        }
        const int col = c0 + frow;
#pragma unroll
        for (int q = 0; q < 16; ++q) {
            const ushort hb = __half_as_ushort(__float2half_rn(acc[q]));
            const unsigned uu = (hb < 0x8000u) ? (unsigned)hb : 0u;
            const int rl = (q & 3) + 8 * (q >> 2) + 4 * fsel;
            const unsigned hi = rowHi[rl], lo = rowLo[rl];
            float oval = 0.f;
            bool dowrite = true;
            if (hi == 0u) {                              // keepall row
                if (uu) oval = __half2float(__ushort_as_half((ushort)uu));
            } else if (uu > hi) {                        // certain keep
                oval = __half2float(__ushort_as_half((ushort)uu));
                atomicAdd(&Acnt[rl], 1u);
            } else if (uu >= lo) {                       // window candidate
                const unsigned p = atomicAdd(&cnum[rl], 1u);
                if (p < CAP) {
                    cand[rl][p] = (uu << 13) | (unsigned)col;
                    dowrite = false;                     // rank phase owns this address
                }                                        // overflow: write 0 here
            }
            if (dowrite) out[(size_t)(m0 + rl) * NN + col] = oval;
        }
    }
    __syncthreads();

    // ---- exact dots for window candidates (frozen fmaf chain == round-3 ordering) ----
    for (int g = tid; g < RPB * CAP; g += 512) {
        const int r = g >> 8, j = g & (CAP - 1);
        const int nc = (int)(cnum[r] < CAP ? cnum[r] : CAP);
        if (j < nc) {
            const int c = (int)(cand[r][j] & 0x1FFFu);
            const float* rb = emb + (size_t)c * DDIM;
            float a = 0.f;
#pragma unroll 8
            for (int k = 0; k < DDIM; ++k) a = fmaf(semb[r][k], rb[k], a);
            cval[r][j] = a;
        }
    }
    __syncthreads();

    // ---- rank (ties -> lower col, matching lax.top_k); write value-or-zero ----
    for (int g = tid; g < RPB * CAP; g += 512) {
        const int r = g >> 8, j = g & (CAP - 1);
        const int nc = (int)(cnum[r] < CAP ? cnum[r] : CAP);
        if (j < nc) {
            const float e = cval[r][j];
            const unsigned pk = cand[r][j];
            const int c = (int)(pk & 0x1FFFu);
            int rk = 0;
            for (int d = 0; d < nc; ++d) {
                const float ed = cval[r][d];
                const int cd = (int)(cand[r][d] & 0x1FFFu);
                rk += (ed > e) || (ed == e && cd < c);
            }
            const bool kept = (Acnt[r] + (unsigned)rk < kp1);
            out[(size_t)(m0 + r) * NN + c] =
                kept ? __half2float(__ushort_as_half((ushort)(pk >> 13))) : 0.f;
        }
    }
}

extern "C" void kernel_launch(void* const* d_in, const int* in_sizes, int n_in,
                              void* d_out, int out_size, void* d_ws, size_t ws_size,
                              hipStream_t stream)
{
    const float* X  = (const float*)d_in[0];
    const float* W1 = (const float*)d_in[1];
    const float* b1 = (const float*)d_in[2];
    const float* W2 = (const float*)d_in[3];
    const float* b2 = (const float*)d_in[4];
    const int* kp1  = (const int*)d_in[5];
    float* out = (float*)d_out;
    float* emb  = (float*)d_ws;                                   // 4 MB f32
    ushort* ebh = (ushort*)((char*)d_ws + (size_t)NN * DDIM * 4); // 2 MB bf16

    mlp_norm_kernel<<<512, 128, 0, stream>>>(X, W1, b1, W2, b2, emb, ebh, 16);
    fused_sim_topk<<<NN / RPB, 512, 0, stream>>>(ebh, emb, out, kp1);
}

// Round 15
// 221.302 us; speedup vs baseline: 1.8274x; 1.8274x over previous
//
#include <hip/hip_runtime.h>
#include <hip/hip_fp16.h>

#define NN 8192
#define DDIM 128
#define DELTA 0.010f    // >= 2*delta_wc; delta_wc <= 2^-8 (bf16 MFMA) + f16 round
#define MAXC 256
#define SIMSTRIDE 16384 // ushorts per row slot (= 32 KB = one f32 output row)

typedef short short8 __attribute__((ext_vector_type(8)));
typedef unsigned short ushort8 __attribute__((ext_vector_type(8)));
typedef float f32x16 __attribute__((ext_vector_type(16)));

__device__ __forceinline__ ushort bf16_rne(float v) {
    const unsigned x = __float_as_uint(v);
    return (ushort)((x + 0x7FFFu + ((x >> 16) & 1u)) >> 16);
}

// ---------------- Kernel 1: MLP (Linear->ReLU->Linear) + L2 normalize + bf16 copy ----
// f32 emb path FROZEN (bit-exact vs round-3/5 passing version); RNE bf16 mirror.
__global__ __launch_bounds__(128, 1)
void mlp_norm_kernel(const float* __restrict__ X, const float* __restrict__ W1,
                     const float* __restrict__ b1, const float* __restrict__ W2,
                     const float* __restrict__ b2, float* __restrict__ emb,
                     ushort* __restrict__ ebh, int rowsPerBlock)
{
    const int t = threadIdx.x;
    float4 w1r[32], w2r[32];
#pragma unroll
    for (int i = 0; i < 32; ++i) w1r[i] = *(const float4*)&W1[t * DDIM + i * 4];
#pragma unroll
    for (int i = 0; i < 32; ++i) w2r[i] = *(const float4*)&W2[t * DDIM + i * 4];
    const float bb1 = b1[t], bb2 = b2[t];

    __shared__ float sx[DDIM];
    __shared__ float sh[DDIM];
    __shared__ float wred[2];

    const int row0 = blockIdx.x * rowsPerBlock;
    for (int r = 0; r < rowsPerBlock; ++r) {
        const int row = row0 + r;
        sx[t] = X[(size_t)row * DDIM + t];
        __syncthreads();
        float acc = bb1;
#pragma unroll
        for (int i = 0; i < 32; ++i) {
            const float4 xv = *(const float4*)&sx[i * 4];
            acc = fmaf(xv.x, w1r[i].x, acc);
            acc = fmaf(xv.y, w1r[i].y, acc);
            acc = fmaf(xv.z, w1r[i].z, acc);
            acc = fmaf(xv.w, w1r[i].w, acc);
        }
        sh[t] = fmaxf(acc, 0.f);
        __syncthreads();
        float acc2 = bb2;
#pragma unroll
        for (int i = 0; i < 32; ++i) {
            const float4 hv = *(const float4*)&sh[i * 4];
            acc2 = fmaf(hv.x, w2r[i].x, acc2);
            acc2 = fmaf(hv.y, w2r[i].y, acc2);
            acc2 = fmaf(hv.z, w2r[i].z, acc2);
            acc2 = fmaf(hv.w, w2r[i].w, acc2);
        }
        float sq = acc2 * acc2;
#pragma unroll
        for (int off = 1; off < 64; off <<= 1) sq += __shfl_xor(sq, off);
        if ((t & 63) == 0) wred[t >> 6] = sq;
        __syncthreads();
        const float ss = wred[0] + wred[1];
        const float inv = 1.0f / fmaxf(sqrtf(ss), 1e-12f);
        const float v = acc2 * inv;
        emb[(size_t)row * DDIM + t] = v;
        ebh[(size_t)row * DDIM + t] = bf16_rne(v);
        __syncthreads();   // protect sx/sh/wred for next iteration
    }
}

// ---------------- Kernel 2: approx sim = ebh @ ebh^T (bf16 MFMA, f16 store in d_out) --
// Math IDENTICAL to r12 (sims bit-identical). NEW: epilogue repacks the C-tile through
// LDS (reusing lA) so global stores are dwordx4 (16B/lane, 4x256B segments/wave)
// instead of 64 scalar 2B stores/thread (64B segments, ~half-rate HBM).
__global__ __launch_bounds__(256)
void simgemm_bf16(const ushort* __restrict__ ebh, ushort* __restrict__ sim)
{
    __shared__ ushort lA[128 * 128];
    __shared__ ushort lB[128 * 128];

    const int tid = threadIdx.x;
    const int bi = blockIdx.x & 63, bj = blockIdx.x >> 6;
    const int m0 = bi << 7, n0 = bj << 7;
    const int lane = tid & 63, wid = tid >> 6;
    const int wr = wid >> 1, wc = wid & 1;
    const int frow = lane & 31, fsel = lane >> 5;

    const int srow0 = tid >> 4, sg = tid & 15;
#pragma unroll
    for (int i = 0; i < 8; ++i) {
        const int row = srow0 + i * 16;
        const int so = row * 128 + ((sg ^ (row & 15)) << 3);
        *(uint4*)&lA[so] = *(const uint4*)&ebh[(size_t)(m0 + row) * DDIM + sg * 8];
        *(uint4*)&lB[so] = *(const uint4*)&ebh[(size_t)(n0 + row) * DDIM + sg * 8];
    }
    __syncthreads();

    f32x16 acc[2][2];
#pragma unroll
    for (int mb = 0; mb < 2; ++mb)
#pragma unroll
        for (int nb = 0; nb < 2; ++nb)
#pragma unroll
            for (int q = 0; q < 16; ++q) acc[mb][nb][q] = 0.f;

#pragma unroll
    for (int ks = 0; ks < 8; ++ks) {
        const int g = ks * 2 + fsel;
        short8 av[2], bv[2];
#pragma unroll
        for (int mb = 0; mb < 2; ++mb) {
            const int r = wr * 64 + mb * 32 + frow;
            av[mb] = *(const short8*)&lA[r * 128 + ((g ^ (r & 15)) << 3)];
        }
#pragma unroll
        for (int nb = 0; nb < 2; ++nb) {
            const int r = wc * 64 + nb * 32 + frow;
            bv[nb] = *(const short8*)&lB[r * 128 + ((g ^ (r & 15)) << 3)];
        }
#pragma unroll
        for (int mb = 0; mb < 2; ++mb)
#pragma unroll
            for (int nb = 0; nb < 2; ++nb)
                acc[mb][nb] = __builtin_amdgcn_mfma_f32_32x32x16_bf16(
                    av[mb], bv[nb], acc[mb][nb], 0, 0, 0);
    }

    // ---- epilogue: repack C-tile (f16) through lA, then coalesced dwordx4 stores ----
    __syncthreads();   // all waves done reading lA/lB
    // C/D layout: col = lane&31, row = (q&3) + 8*(q>>2) + 4*(lane>>5)  [verified r7-r12]
#pragma unroll
    for (int mb = 0; mb < 2; ++mb)
#pragma unroll
        for (int nb = 0; nb < 2; ++nb) {
            const int cl = wc * 64 + nb * 32 + (lane & 31);
#pragma unroll
            for (int q = 0; q < 16; ++q) {
                const int rl = wr * 64 + mb * 32 + (q & 3) + 8 * (q >> 2) + 4 * fsel;
                lA[rl * 128 + cl] = __half_as_ushort(__float2half_rn(acc[mb][nb][q]));
            }
        }
    __syncthreads();
    // thread t: rows (t>>4) + 16i, col chunk (t&15)*8 -> 16 lanes = 256B/row contiguous
    {
        const int rr0 = tid >> 4, cc = (tid & 15) * 8;
#pragma unroll
        for (int i = 0; i < 8; ++i) {
            const int row = rr0 + i * 16;
            *(uint4*)&sim[(size_t)(m0 + row) * SIMSTRIDE + n0 + cc] =
                *(const uint4*)&lA[row * 128 + cc];
        }
    }
}

// ---------------- Kernel 3: top-kp1 on f16 sims (histogram + bin-bracket) + fixup ----
// Level-1 256-bin histogram (f16 bits [13:6]) -> boundary bin B; cut t-hat in [L,H]
// (bin bounds). Window [L-DELTA, H+DELTA] (r14-PROVEN logic): certain-keeps above,
// window candidates recomputed EXACTLY (frozen fmaf chain == round-3 ordering), ranked
// with lax.top_k tie-breaking. Single writer per address (write phase reads bitmap).
__global__ __launch_bounds__(256)
void topk_relu_kernel(float* __restrict__ out, const float* __restrict__ emb,
                      const int* __restrict__ kp1p)
{
    const int row = blockIdx.x;
    const int t = threadIdx.x;
    const int w = t >> 6;
    const int lane = t & 63;
    const unsigned kp1 = (unsigned)kp1p[0];
    const ushort* simrow = (const ushort*)out + (size_t)row * SIMSTRIDE;
    float* rowp = out + (size_t)row * NN;

    __shared__ unsigned bitmap[NN / 32];
    __shared__ float semb[DDIM];
    __shared__ unsigned hist[4][256];
    __shared__ unsigned wpart[4];
    __shared__ unsigned sHL[2];     // 0: hi16, 1: lo16
    __shared__ int cidx[MAXC];
    __shared__ float cval[MAXC];
    __shared__ int cnum;

    bitmap[t] = 0;
    hist[0][t] = 0; hist[1][t] = 0; hist[2][t] = 0; hist[3][t] = 0;
    if (t == 0) cnum = 0;
    if (t < DDIM) semb[t] = emb[(size_t)row * DDIM + t];
    __syncthreads();

    // load 32 f16/thread (coalesced 16B), zero non-positives, level-1 histogram
    unsigned u[32];
#pragma unroll
    for (int i = 0; i < 4; ++i) {
        const ushort8 v8 = *(const ushort8*)&simrow[i * 2048 + t * 8];
#pragma unroll
        for (int j = 0; j < 8; ++j) {
            const unsigned uu = (v8[j] < 0x8000u) ? (unsigned)v8[j] : 0u;
            u[i * 8 + j] = uu;
            if (uu) atomicAdd(&hist[w][uu >> 6], 1u);
        }
    }
    __syncthreads();

    // ---- suffix scan over 256 bins (thread t owns bin t) -> boundary bin bracket ----
    const unsigned tot = hist[0][t] + hist[1][t] + hist[2][t] + hist[3][t];
    unsigned s = tot;
#pragma unroll
    for (int off = 1; off < 64; off <<= 1) {
        const unsigned o = __shfl_down(s, off);
        if (lane + off < 64) s += o;
    }
    if (lane == 0) wpart[w] = s;
    __syncthreads();
    unsigned addhi = 0;
    for (int w2 = w + 1; w2 < 4; ++w2) addhi += wpart[w2];
    const unsigned S = s + addhi;               // count(bin >= t)
    if (t == 0 && wpart[0] + wpart[1] + wpart[2] + wpart[3] < kp1) {
        sHL[0] = 0u; sHL[1] = 0xFFFFFFFFu;      // keepall: keep every positive
    }
    if (S >= kp1 && S - tot < kp1) {            // unique boundary bin B = t
        const unsigned B = (unsigned)t;
        const float L = __half2float(__ushort_as_half((ushort)(B << 6)));
        const float H = __half2float(__ushort_as_half((ushort)((B << 6) | 63u)));
        const unsigned hi =
            (unsigned)__half_as_ushort(__float2half_rn(H + DELTA)) + 1u;
        const float lof = L - DELTA;
        unsigned lo;
        if (lof <= 0.f) lo = 1u;
        else { const unsigned l2 = __half_as_ushort(__float2half_rn(lof));
               lo = (l2 > 1u) ? l2 - 1u : 1u; }
        sHL[0] = hi; sHL[1] = lo;
    }
    __syncthreads();

    const unsigned hi16 = sHL[0], lo16 = sHL[1];
    if (hi16 != 0u) {
        // A = #(v > hi) certainly kept; gather window candidates
        unsigned acnt = 0;
#pragma unroll
        for (int q = 0; q < 32; ++q) {
            const unsigned uu = u[q];
            if (uu > hi16) ++acnt;
            else if (uu >= lo16) {
                const int p = atomicAdd(&cnum, 1);
                if (p < MAXC) cidx[p] = (q >> 3) * 2048 + t * 8 + (q & 7);
            }
        }
#pragma unroll
        for (int off = 1; off < 64; off <<= 1) acnt += __shfl_xor(acnt, off);
        if (lane == 0) wpart[w] = acnt;
        __syncthreads();
        const unsigned A = wpart[0] + wpart[1] + wpart[2] + wpart[3];
        const int nc = cnum < MAXC ? cnum : MAXC;

        // exact recompute: frozen serial fmaf chain, ascending k (== round-3 ordering)
        if (t < nc) {
            const float* rb = emb + (size_t)cidx[t] * DDIM;
            float a = 0.f;
#pragma unroll 8
            for (int k = 0; k < DDIM; ++k) a = fmaf(semb[k], rb[k], a);
            cval[t] = a;
        }
        __syncthreads();
        // rank among candidates (ties -> lower index wins, matching lax.top_k)
        if (t < nc) {
            const float e = cval[t];
            const int my = cidx[t];
            int r = 0;
            for (int d = 0; d < nc; ++d)
                r += (cval[d] > e) || (cval[d] == e && cidx[d] < my);
            if (A + (unsigned)r < kp1)
                atomicOr(&bitmap[my >> 5], 1u << (my & 31));
        }
        __syncthreads();
    } else {
        __syncthreads();   // keepall path: keep barrier count uniform
    }

    // ---- write full f32 row: certain-aboves + ranked-in candidates; zeros elsewhere --
#pragma unroll
    for (int i = 0; i < 4; ++i) {
        const int col0 = i * 2048 + t * 8;
        float o[8];
#pragma unroll
        for (int j = 0; j < 8; ++j) {
            const unsigned uu = u[i * 8 + j];
            const int idx = col0 + j;
            const bool keep = (uu > hi16) ||
                              (uu >= lo16 &&
                               ((bitmap[idx >> 5] >> (idx & 31)) & 1u));
            o[j] = keep ? __half2float(__ushort_as_half((ushort)uu)) : 0.f;
        }
        *(float4*)&rowp[col0]     = make_float4(o[0], o[1], o[2], o[3]);
        *(float4*)&rowp[col0 + 4] = make_float4(o[4], o[5], o[6], o[7]);
    }
}

extern "C" void kernel_launch(void* const* d_in, const int* in_sizes, int n_in,
                              void* d_out, int out_size, void* d_ws, size_t ws_size,
                              hipStream_t stream)
{
    const float* X  = (const float*)d_in[0];
    const float* W1 = (const float*)d_in[1];
    const float* b1 = (const float*)d_in[2];
    const float* W2 = (const float*)d_in[3];
    const float* b2 = (const float*)d_in[4];
    const int* kp1  = (const int*)d_in[5];
    float* out = (float*)d_out;
    float* emb  = (float*)d_ws;                                   // 4 MB f32
    ushort* ebh = (ushort*)((char*)d_ws + (size_t)NN * DDIM * 4); // 2 MB bf16

    mlp_norm_kernel<<<512, 128, 0, stream>>>(X, W1, b1, W2, b2, emb, ebh, 16);
    simgemm_bf16<<<4096, 256, 0, stream>>>(ebh, (ushort*)out);
    topk_relu_kernel<<<NN, 256, 0, stream>>>(out, emb, kp1);
}

// Round 16
// 218.442 us; speedup vs baseline: 1.8513x; 1.0131x over previous
//
#include <hip/hip_runtime.h>
#include <hip/hip_fp16.h>

#define NN 8192
#define DDIM 128
#define DELTA 0.010f    // >= 2*delta_wc; delta_wc <= 2^-8 (bf16 MFMA) + f16 round
#define MAXC 256
#define SIMSTRIDE 16384 // ushorts per row slot (= 32 KB = one f32 output row)
#define HC 8            // histogram copies (bank-spread)
#define HSTRIDE 260     // copy stride in u32: 260 % 32 = 4 -> 8 distinct banks

typedef short short8 __attribute__((ext_vector_type(8)));
typedef unsigned short ushort8 __attribute__((ext_vector_type(8)));
typedef float f32x16 __attribute__((ext_vector_type(16)));

__device__ __forceinline__ ushort bf16_rne(float v) {
    const unsigned x = __float_as_uint(v);
    return (ushort)((x + 0x7FFFu + ((x >> 16) & 1u)) >> 16);
}

// ---------------- Kernel 1: MLP (Linear->ReLU->Linear) + L2 normalize + bf16 copy ----
// f32 emb path FROZEN (bit-exact vs round-3/5 passing version); RNE bf16 mirror.
__global__ __launch_bounds__(128, 1)
void mlp_norm_kernel(const float* __restrict__ X, const float* __restrict__ W1,
                     const float* __restrict__ b1, const float* __restrict__ W2,
                     const float* __restrict__ b2, float* __restrict__ emb,
                     ushort* __restrict__ ebh, int rowsPerBlock)
{
    const int t = threadIdx.x;
    float4 w1r[32], w2r[32];
#pragma unroll
    for (int i = 0; i < 32; ++i) w1r[i] = *(const float4*)&W1[t * DDIM + i * 4];
#pragma unroll
    for (int i = 0; i < 32; ++i) w2r[i] = *(const float4*)&W2[t * DDIM + i * 4];
    const float bb1 = b1[t], bb2 = b2[t];

    __shared__ float sx[DDIM];
    __shared__ float sh[DDIM];
    __shared__ float wred[2];

    const int row0 = blockIdx.x * rowsPerBlock;
    for (int r = 0; r < rowsPerBlock; ++r) {
        const int row = row0 + r;
        sx[t] = X[(size_t)row * DDIM + t];
        __syncthreads();
        float acc = bb1;
#pragma unroll
        for (int i = 0; i < 32; ++i) {
            const float4 xv = *(const float4*)&sx[i * 4];
            acc = fmaf(xv.x, w1r[i].x, acc);
            acc = fmaf(xv.y, w1r[i].y, acc);
            acc = fmaf(xv.z, w1r[i].z, acc);
            acc = fmaf(xv.w, w1r[i].w, acc);
        }
        sh[t] = fmaxf(acc, 0.f);
        __syncthreads();
        float acc2 = bb2;
#pragma unroll
        for (int i = 0; i < 32; ++i) {
            const float4 hv = *(const float4*)&sh[i * 4];
            acc2 = fmaf(hv.x, w2r[i].x, acc2);
            acc2 = fmaf(hv.y, w2r[i].y, acc2);
            acc2 = fmaf(hv.z, w2r[i].z, acc2);
            acc2 = fmaf(hv.w, w2r[i].w, acc2);
        }
        float sq = acc2 * acc2;
#pragma unroll
        for (int off = 1; off < 64; off <<= 1) sq += __shfl_xor(sq, off);
        if ((t & 63) == 0) wred[t >> 6] = sq;
        __syncthreads();
        const float ss = wred[0] + wred[1];
        const float inv = 1.0f / fmaxf(sqrtf(ss), 1e-12f);
        const float v = acc2 * inv;
        emb[(size_t)row * DDIM + t] = v;
        ebh[(size_t)row * DDIM + t] = bf16_rne(v);
        __syncthreads();   // protect sx/sh/wred for next iteration
    }
}

// ---------------- Kernel 2: approx sim = ebh @ ebh^T (bf16 MFMA, f16 store in d_out) --
// BYTE-EXACT revert to round-12's passing version (202.7 us pipeline). No repack.
__global__ __launch_bounds__(256)
void simgemm_bf16(const ushort* __restrict__ ebh, ushort* __restrict__ sim)
{
    __shared__ ushort lA[128 * 128];
    __shared__ ushort lB[128 * 128];

    const int tid = threadIdx.x;
    const int bi = blockIdx.x & 63, bj = blockIdx.x >> 6;
    const int m0 = bi << 7, n0 = bj << 7;
    const int lane = tid & 63, wid = tid >> 6;
    const int wr = wid >> 1, wc = wid & 1;
    const int frow = lane & 31, fsel = lane >> 5;

    const int srow0 = tid >> 4, sg = tid & 15;
#pragma unroll
    for (int i = 0; i < 8; ++i) {
        const int row = srow0 + i * 16;
        const int so = row * 128 + ((sg ^ (row & 15)) << 3);
        *(uint4*)&lA[so] = *(const uint4*)&ebh[(size_t)(m0 + row) * DDIM + sg * 8];
        *(uint4*)&lB[so] = *(const uint4*)&ebh[(size_t)(n0 + row) * DDIM + sg * 8];
    }
    __syncthreads();

    f32x16 acc[2][2];
#pragma unroll
    for (int mb = 0; mb < 2; ++mb)
#pragma unroll
        for (int nb = 0; nb < 2; ++nb)
#pragma unroll
            for (int q = 0; q < 16; ++q) acc[mb][nb][q] = 0.f;

#pragma unroll
    for (int ks = 0; ks < 8; ++ks) {
        const int g = ks * 2 + fsel;
        short8 av[2], bv[2];
#pragma unroll
        for (int mb = 0; mb < 2; ++mb) {
            const int r = wr * 64 + mb * 32 + frow;
            av[mb] = *(const short8*)&lA[r * 128 + ((g ^ (r & 15)) << 3)];
        }
#pragma unroll
        for (int nb = 0; nb < 2; ++nb) {
            const int r = wc * 64 + nb * 32 + frow;
            bv[nb] = *(const short8*)&lB[r * 128 + ((g ^ (r & 15)) << 3)];
        }
#pragma unroll
        for (int mb = 0; mb < 2; ++mb)
#pragma unroll
            for (int nb = 0; nb < 2; ++nb)
                acc[mb][nb] = __builtin_amdgcn_mfma_f32_32x32x16_bf16(
                    av[mb], bv[nb], acc[mb][nb], 0, 0, 0);
    }

    // C/D layout: col = lane&31, row = (q&3) + 8*(q>>2) + 4*(lane>>5)  [verified r7-r12]
#pragma unroll
    for (int mb = 0; mb < 2; ++mb)
#pragma unroll
        for (int nb = 0; nb < 2; ++nb)
#pragma unroll
            for (int q = 0; q < 16; ++q) {
                const int rl = (q & 3) + 8 * (q >> 2) + 4 * fsel;
                const int grow = m0 + wr * 64 + mb * 32 + rl;
                const int gcol = n0 + wc * 64 + nb * 32 + (lane & 31);
                sim[(size_t)grow * SIMSTRIDE + gcol] =
                    __half_as_ushort(__float2half_rn(acc[mb][nb][q]));
            }
}

// ---------------- Kernel 3: top-kp1 on f16 sims (8-copy histogram + bin-bracket) -----
// CHANGE 1: histogram in 8 bank-spread copies (copy = t&7, stride 260) -> same-bin
// atomic serialization ~8x lower than one-copy-per-wave. CHANGE 2 (r14/r15-proven):
// boundary-bin bracket window [L-DELTA, H+DELTA], no level-2 sweep. Window candidates
// recomputed EXACTLY (frozen fmaf chain == round-3 ordering), ranked lax.top_k-style.
__global__ __launch_bounds__(256)
void topk_relu_kernel(float* __restrict__ out, const float* __restrict__ emb,
                      const int* __restrict__ kp1p)
{
    const int row = blockIdx.x;
    const int t = threadIdx.x;
    const int w = t >> 6;
    const int lane = t & 63;
    const unsigned kp1 = (unsigned)kp1p[0];
    const ushort* simrow = (const ushort*)out + (size_t)row * SIMSTRIDE;
    float* rowp = out + (size_t)row * NN;

    __shared__ unsigned bitmap[NN / 32];
    __shared__ float semb[DDIM];
    __shared__ unsigned hist[HC * HSTRIDE];   // 8 copies, bank-spread
    __shared__ unsigned wpart[4];
    __shared__ unsigned sHL[2];     // 0: hi16, 1: lo16
    __shared__ int cidx[MAXC];
    __shared__ float cval[MAXC];
    __shared__ int cnum;

    bitmap[t] = 0;
    for (int i = t; i < HC * HSTRIDE; i += 256) hist[i] = 0u;
    if (t == 0) cnum = 0;
    if (t < DDIM) semb[t] = emb[(size_t)row * DDIM + t];
    __syncthreads();

    // load 32 f16/thread (coalesced 16B), zero non-positives, 8-copy histogram
    const int hc = (t & 7) * HSTRIDE;
    unsigned u[32];
#pragma unroll
    for (int i = 0; i < 4; ++i) {
        const ushort8 v8 = *(const ushort8*)&simrow[i * 2048 + t * 8];
#pragma unroll
        for (int j = 0; j < 8; ++j) {
            const unsigned uu = (v8[j] < 0x8000u) ? (unsigned)v8[j] : 0u;
            u[i * 8 + j] = uu;
            if (uu) atomicAdd(&hist[hc + (uu >> 6)], 1u);
        }
    }
    __syncthreads();

    // ---- suffix scan over 256 bins (thread t owns bin t) -> boundary bin bracket ----
    unsigned tot = 0;
#pragma unroll
    for (int c = 0; c < HC; ++c) tot += hist[c * HSTRIDE + t];
    unsigned s = tot;
#pragma unroll
    for (int off = 1; off < 64; off <<= 1) {
        const unsigned o = __shfl_down(s, off);
        if (lane + off < 64) s += o;
    }
    if (lane == 0) wpart[w] = s;
    __syncthreads();
    unsigned addhi = 0;
    for (int w2 = w + 1; w2 < 4; ++w2) addhi += wpart[w2];
    const unsigned S = s + addhi;               // count(bin >= t)
    if (t == 0 && wpart[0] + wpart[1] + wpart[2] + wpart[3] < kp1) {
        sHL[0] = 0u; sHL[1] = 0xFFFFFFFFu;      // keepall: keep every positive
    }
    if (S >= kp1 && S - tot < kp1) {            // unique boundary bin B = t
        const unsigned B = (unsigned)t;
        const float L = __half2float(__ushort_as_half((ushort)(B << 6)));
        const float H = __half2float(__ushort_as_half((ushort)((B << 6) | 63u)));
        const unsigned hi =
            (unsigned)__half_as_ushort(__float2half_rn(H + DELTA)) + 1u;
        const float lof = L - DELTA;
        unsigned lo;
        if (lof <= 0.f) lo = 1u;
        else { const unsigned l2 = __half_as_ushort(__float2half_rn(lof));
               lo = (l2 > 1u) ? l2 - 1u : 1u; }
        sHL[0] = hi; sHL[1] = lo;
    }
    __syncthreads();

    const unsigned hi16 = sHL[0], lo16 = sHL[1];
    if (hi16 != 0u) {
        // A = #(v > hi) certainly kept; gather window candidates
        unsigned acnt = 0;
#pragma unroll
        for (int q = 0; q < 32; ++q) {
            const unsigned uu = u[q];
            if (uu > hi16) ++acnt;
            else if (uu >= lo16) {
                const int p = atomicAdd(&cnum, 1);
                if (p < MAXC) cidx[p] = (q >> 3) * 2048 + t * 8 + (q & 7);
            }
        }
#pragma unroll
        for (int off = 1; off < 64; off <<= 1) acnt += __shfl_xor(acnt, off);
        if (lane == 0) wpart[w] = acnt;
        __syncthreads();
        const unsigned A = wpart[0] + wpart[1] + wpart[2] + wpart[3];
        const int nc = cnum < MAXC ? cnum : MAXC;

        // exact recompute: frozen serial fmaf chain, ascending k (== round-3 ordering)
        if (t < nc) {
            const float* rb = emb + (size_t)cidx[t] * DDIM;
            float a = 0.f;
#pragma unroll 8
            for (int k = 0; k < DDIM; ++k) a = fmaf(semb[k], rb[k], a);
            cval[t] = a;
        }
        __syncthreads();
        // rank among candidates (ties -> lower index wins, matching lax.top_k)
        if (t < nc) {
            const float e = cval[t];
            const int my = cidx[t];
            int r = 0;
            for (int d = 0; d < nc; ++d)
                r += (cval[d] > e) || (cval[d] == e && cidx[d] < my);
            if (A + (unsigned)r < kp1)
                atomicOr(&bitmap[my >> 5], 1u << (my & 31));
        }
        __syncthreads();
    } else {
        __syncthreads();   // keepall path: keep barrier count uniform
    }

    // ---- write full f32 row: certain-aboves + ranked-in candidates; zeros elsewhere --
#pragma unroll
    for (int i = 0; i < 4; ++i) {
        const int col0 = i * 2048 + t * 8;
        float o[8];
#pragma unroll
        for (int j = 0; j < 8; ++j) {
            const unsigned uu = u[i * 8 + j];
            const int idx = col0 + j;
            const bool keep = (uu > hi16) ||
                              (uu >= lo16 &&
                               ((bitmap[idx >> 5] >> (idx & 31)) & 1u));
            o[j] = keep ? __half2float(__ushort_as_half((ushort)uu)) : 0.f;
        }
        *(float4*)&rowp[col0]     = make_float4(o[0], o[1], o[2], o[3]);
        *(float4*)&rowp[col0 + 4] = make_float4(o[4], o[5], o[6], o[7]);
    }
}

extern "C" void kernel_launch(void* const* d_in, const int* in_sizes, int n_in,
                              void* d_out, int out_size, void* d_ws, size_t ws_size,
                              hipStream_t stream)
{
    const float* X  = (const float*)d_in[0];
    const float* W1 = (const float*)d_in[1];
    const float* b1 = (const float*)d_in[2];
    const float* W2 = (const float*)d_in[3];
    const float* b2 = (const float*)d_in[4];
    const int* kp1  = (const int*)d_in[5];
    float* out = (float*)d_out;
    float* emb  = (float*)d_ws;                                   // 4 MB f32
    ushort* ebh = (ushort*)((char*)d_ws + (size_t)NN * DDIM * 4); // 2 MB bf16

    mlp_norm_kernel<<<512, 128, 0, stream>>>(X, W1, b1, W2, b2, emb, ebh, 16);
    simgemm_bf16<<<4096, 256, 0, stream>>>(ebh, (ushort*)out);
    topk_relu_kernel<<<NN, 256, 0, stream>>>(out, emb, kp1);
}